// Round 13
// baseline (357.767 us; speedup 1.0000x reference)
//
#include <hip/hip_runtime.h>
#include <hip/hip_bf16.h>
#include <hip/hip_fp16.h>

// GCN: h = relu(GCN(x,W1,b1)); h = relu(GCN(h,W2,b2)); out = h @ Wfc + bfc
// GCN(x,W,b)[d] = dis[d] * ( sum_{(s,d) in E} hs[s] + hs[d] ) + b
//   where hs[v] = (x[v]@W) * dis[v],  dis[v] = rsqrt(1 + indeg(v))
//
// Round-13: same pipeline as round-12 (binned counting sort -> packed
// dst-sorted CSR; fp16 h1s/h2s; wide multi-edge gathers) but k_agg12 is
// BATCHED: 64 nodes/block (16/wave), two-phase (gather->LDS rows, one
// barrier, then gemm2 from LDS) so the W2-column register preload and the
// block barrier amortize over 64 nodes instead of 4.

#define SCAN_CHUNK 1024
#define BSHIFT 7
#define BSIZE 128            // dsts per bucket
#define B1 256               // blocks in hist/binscatter passes

__device__ inline void f4fma(float4& a, float s, const float4& b) {
    a.x = fmaf(s, b.x, a.x); a.y = fmaf(s, b.y, a.y);
    a.z = fmaf(s, b.z, a.z); a.w = fmaf(s, b.w, a.w);
}
__device__ inline void f4add(float4& a, const float4& b) {
    a.x += b.x; a.y += b.y; a.z += b.z; a.w += b.w;
}
__device__ inline void f4red(float4& a, int off) {
    a.x += __shfl_xor(a.x, off); a.y += __shfl_xor(a.y, off);
    a.z += __shfl_xor(a.z, off); a.w += __shfl_xor(a.w, off);
}
// 8 halves (16 B) -> two float4 (single dwordx4 load)
__device__ inline void h8load(const __half* p, float4& a, float4& b) {
    uint4 r = *(const uint4*)p;
    __half2* h = (__half2*)&r;
    float2 f0 = __half22float2(h[0]);
    float2 f1 = __half22float2(h[1]);
    float2 f2 = __half22float2(h[2]);
    float2 f3 = __half22float2(h[3]);
    a = make_float4(f0.x, f0.y, f1.x, f1.y);
    b = make_float4(f2.x, f2.y, f3.x, f3.y);
}
__device__ inline void h4store(__half* p, float4 v) {
    __half2 a = __floats2half2_rn(v.x, v.y);
    __half2 b = __floats2half2_rn(v.z, v.w);
    uint2 r; r.x = *(uint*)&a; r.y = *(uint*)&b;
    *(uint2*)p = r;
}

// ---- generic exclusive scan (m ints, nblk = ceil(m/1024) <= 256) ----
__global__ void k_gscan1(const int* __restrict__ in, int* __restrict__ part, int m) {
    int t = threadIdx.x;
    int base = blockIdx.x * SCAN_CHUNK + t * 4;
    int s = 0;
    for (int u = 0; u < 4; ++u) { int i = base + u; if (i < m) s += in[i]; }
    for (int o = 32; o; o >>= 1) s += __shfl_down(s, o);
    __shared__ int ws[4];
    if ((t & 63) == 0) ws[t >> 6] = s;
    __syncthreads();
    if (t == 0) part[blockIdx.x] = ws[0] + ws[1] + ws[2] + ws[3];
}

__global__ void k_gscan2(const int* __restrict__ in, const int* __restrict__ part,
                         int* __restrict__ out, int m, int nblk) {
    int t = threadIdx.x;
    int b = blockIdx.x;
    int pv = (t < b && t < nblk) ? part[t] : 0;
    int ps = pv;
    for (int o = 32; o; o >>= 1) ps += __shfl_down(ps, o);
    __shared__ int sh[4];
    if ((t & 63) == 0) sh[t >> 6] = ps;
    __syncthreads();
    int blockoff = sh[0] + sh[1] + sh[2] + sh[3];

    int base = b * SCAN_CHUNK + t * 4;
    int v0 = 0, v1 = 0, v2 = 0, v3 = 0;
    if (base + 0 < m) v0 = in[base + 0];
    if (base + 1 < m) v1 = in[base + 1];
    if (base + 2 < m) v2 = in[base + 2];
    if (base + 3 < m) v3 = in[base + 3];
    int tot = v0 + v1 + v2 + v3;
    int lane = t & 63, wid = t >> 6;
    int incl = tot;
    for (int o = 1; o < 64; o <<= 1) { int u = __shfl_up(incl, o); if (lane >= o) incl += u; }
    int excl = incl - tot;
    __shared__ int wt[4];
    if (lane == 63) wt[wid] = incl;
    __syncthreads();
    int woff = 0;
    for (int w = 0; w < wid; ++w) woff += wt[w];
    int off = blockoff + woff + excl;
    if (base + 0 < m) out[base + 0] = off;
    if (base + 1 < m) out[base + 1] = off + v0;
    if (base + 2 < m) out[base + 2] = off + v0 + v1;
    if (base + 3 < m) out[base + 3] = off + v0 + v1 + v2;
}

// ---- pass 1a: per-block bucket histogram (LDS atomics, int4 reads) ----
__global__ __launch_bounds__(256) void k_hist(const int* __restrict__ dst,
                                              int* __restrict__ ghist,
                                              int e, int echunk, int nbuck) {
    extern __shared__ int h[];   // nbuck ints
    int t = threadIdx.x, b = blockIdx.x;
    for (int i = t; i < nbuck; i += 256) h[i] = 0;
    __syncthreads();
    int s = b * echunk, epd = min(e, s + echunk);
    for (int i = s + t * 4; i < epd; i += 1024) {
        if (i + 3 < epd) {
            int4 d4 = *(const int4*)&dst[i];
            atomicAdd(&h[d4.x >> BSHIFT], 1);
            atomicAdd(&h[d4.y >> BSHIFT], 1);
            atomicAdd(&h[d4.z >> BSHIFT], 1);
            atomicAdd(&h[d4.w >> BSHIFT], 1);
        } else {
            for (int u = i; u < epd; ++u) atomicAdd(&h[dst[u] >> BSHIFT], 1);
        }
    }
    __syncthreads();
    for (int k = t; k < nbuck; k += 256)
        ghist[k * B1 + b] = h[k];
}

// ---- pass 1b: scatter packed (src<<7|dlow) into bucket-ordered ebuf ----
__global__ __launch_bounds__(256) void k_binscatter(
        const int* __restrict__ src, const int* __restrict__ dst,
        const int* __restrict__ ghist_s, int* __restrict__ ebuf,
        int e, int echunk, int nbuck) {
    extern __shared__ int cur[];   // nbuck ints
    int t = threadIdx.x, b = blockIdx.x;
    for (int k = t; k < nbuck; k += 256)
        cur[k] = ghist_s[k * B1 + b];
    __syncthreads();
    int s = b * echunk, epd = min(e, s + echunk);
    for (int i = s + t * 4; i < epd; i += 1024) {
        if (i + 3 < epd) {
            int4 d4 = *(const int4*)&dst[i];
            int4 s4 = *(const int4*)&src[i];
            int p0 = atomicAdd(&cur[d4.x >> BSHIFT], 1);
            int p1 = atomicAdd(&cur[d4.y >> BSHIFT], 1);
            int p2 = atomicAdd(&cur[d4.z >> BSHIFT], 1);
            int p3 = atomicAdd(&cur[d4.w >> BSHIFT], 1);
            ebuf[p0] = (s4.x << BSHIFT) | (d4.x & (BSIZE - 1));
            ebuf[p1] = (s4.y << BSHIFT) | (d4.y & (BSIZE - 1));
            ebuf[p2] = (s4.z << BSHIFT) | (d4.z & (BSIZE - 1));
            ebuf[p3] = (s4.w << BSHIFT) | (d4.w & (BSIZE - 1));
        } else {
            for (int u = i; u < epd; ++u) {
                int d = dst[u];
                int pos = atomicAdd(&cur[d >> BSHIFT], 1);
                ebuf[pos] = (src[u] << BSHIFT) | (d & (BSIZE - 1));
            }
        }
    }
}

// ---- pass 2: per-bucket dst counting sort -> ebuf2 (bucket-local CSR) ----
__global__ __launch_bounds__(256) void k_csr(
        const int* __restrict__ ebuf, const int* __restrict__ ghist_s,
        int* __restrict__ ebuf2, int* __restrict__ rowptr, int* __restrict__ degi,
        float* __restrict__ dis, int n, int e, int nbuck) {
    int k = blockIdx.x, t = threadIdx.x;
    int estart = ghist_s[k * B1];
    int eend = (k + 1 < nbuck) ? ghist_s[(k + 1) * B1] : e;
    __shared__ int cnt[BSIZE];
    __shared__ int cur[BSIZE];
    __shared__ int wt[4];
    if (t < BSIZE) cnt[t] = 0;
    __syncthreads();
    for (int i = estart + t; i < eend; i += 256)
        atomicAdd(&cnt[ebuf[i] & (BSIZE - 1)], 1);
    __syncthreads();
    int v = (t < BSIZE) ? cnt[t] : 0;
    int lane = t & 63, wid = t >> 6;
    int incl = v;
    for (int o = 1; o < 64; o <<= 1) { int u = __shfl_up(incl, o); if (lane >= o) incl += u; }
    if (lane == 63) wt[wid] = incl;
    __syncthreads();
    int woff = (wid == 1) ? wt[0] : 0;
    int excl = woff + incl - v;
    if (t < BSIZE) {
        cur[t] = estart + excl;
        int node = k * BSIZE + t;
        if (node < n) {
            rowptr[node] = estart + excl;
            degi[node]   = v;
            dis[node]    = rsqrtf((float)(v + 1));
        }
    }
    __syncthreads();
    for (int i = estart + t; i < eend; i += 256) {
        int w = ebuf[i];
        int pos = atomicAdd(&cur[w & (BSIZE - 1)], 1);
        ebuf2[pos] = w;      // packed (src<<7 | dlow), dst-sorted
    }
}

// h1s = fp16( (x @ W1) * dis ) — outer-product GEMM, block tile 64x64, K=128.
#define SA 132
__global__ __launch_bounds__(256) void k_gemm1(
        const float* __restrict__ x, const float* __restrict__ W1,
        const float* __restrict__ dis, __half* __restrict__ h1s, int n) {
    __shared__ float Xs[64 * SA];    // 33 KB
    __shared__ float Ws[128 * 64];   // 32 KB
    int t = threadIdx.x;
    int nbase = blockIdx.x * 64;
    for (int i = t; i < 2048; i += 256)
        ((float4*)Ws)[i] = ((const float4*)W1)[i];
    for (int i = t; i < 2048; i += 256) {
        int row = i >> 5, q = i & 31;
        int r = nbase + row; if (r >= n) r = n - 1;
        float4 v = ((const float4*)(x + (size_t)r * 128))[q];
        *(float4*)&Xs[row * SA + q * 4] = v;
    }
    __syncthreads();
    int wid = t >> 6, lane = t & 63;
    int lx = lane & 7, ly = lane >> 3;
    int wm = wid & 1, wn = wid >> 1;
    int row0 = wm * 32 + ly * 4;
    int col0 = wn * 32 + lx * 4;
    float4 acc0 = {0.f,0.f,0.f,0.f}, acc1 = acc0, acc2 = acc0, acc3 = acc0;
#pragma unroll 4
    for (int k4 = 0; k4 < 32; ++k4) {
        int k = k4 * 4;
        float4 a0 = *(const float4*)&Xs[(row0 + 0) * SA + k];
        float4 a1 = *(const float4*)&Xs[(row0 + 1) * SA + k];
        float4 a2 = *(const float4*)&Xs[(row0 + 2) * SA + k];
        float4 a3 = *(const float4*)&Xs[(row0 + 3) * SA + k];
        float4 b0 = *(const float4*)&Ws[(k + 0) * 64 + col0];
        float4 b1 = *(const float4*)&Ws[(k + 1) * 64 + col0];
        float4 b2 = *(const float4*)&Ws[(k + 2) * 64 + col0];
        float4 b3 = *(const float4*)&Ws[(k + 3) * 64 + col0];
        f4fma(acc0, a0.x, b0); f4fma(acc0, a0.y, b1); f4fma(acc0, a0.z, b2); f4fma(acc0, a0.w, b3);
        f4fma(acc1, a1.x, b0); f4fma(acc1, a1.y, b1); f4fma(acc1, a1.z, b2); f4fma(acc1, a1.w, b3);
        f4fma(acc2, a2.x, b0); f4fma(acc2, a2.y, b1); f4fma(acc2, a2.z, b2); f4fma(acc2, a2.w, b3);
        f4fma(acc3, a3.x, b0); f4fma(acc3, a3.y, b1); f4fma(acc3, a3.z, b2); f4fma(acc3, a3.w, b3);
    }
    int grow = nbase + row0;
#pragma unroll
    for (int r = 0; r < 4; ++r) {
        int rr = grow + r;
        if (rr < n) {
            float d = dis[rr];
            float4 o = (r == 0) ? acc0 : (r == 1) ? acc1 : (r == 2) ? acc2 : acc3;
            o.x *= d; o.y *= d; o.z *= d; o.w *= d;
            h4store(&h1s[(size_t)rr * 64 + col0], o);
        }
    }
}

// Layer-1 aggregation + relu/b1 + gemm2, batched 64 nodes/block (16/wave).
// Phase 1: each wave gathers its 16 nodes (8 edges per dwordx4; fp16 rows)
// and parks relu'd h1r rows in its private LDS slab (no barrier needed).
// Phase 2: one __syncthreads, then gemm2 from LDS with W2 column preloaded
// ONCE per block (32 VGPRs/lane) -> h2s (fp16).
__global__ __launch_bounds__(256) void k_agg12(
        const __half* __restrict__ h1s, const int* __restrict__ ents,
        const int* __restrict__ rowptr, const int* __restrict__ degi,
        const float* __restrict__ dis, const float* __restrict__ b1,
        const float* __restrict__ W2, __half* __restrict__ h2s, int n) {
    __shared__ float h1row[4][16][68];   // 17408 B
    __shared__ float disW[4][16];
    int wid = threadIdx.x >> 6, lane = threadIdx.x & 63;
    int eg = lane >> 3;
    int fq = (lane & 7) * 8;           // half-index of this lane's 8 features
    int c = lane & 31, hh = lane >> 5;
    // preload W2 column c, k-range [hh*32, hh*32+32) -> 32 VGPRs (per block)
    float w2r[32];
#pragma unroll
    for (int j = 0; j < 32; ++j)
        w2r[j] = W2[(hh * 32 + j) * 32 + c];
    int nbase = blockIdx.x * 64 + wid * 16;
    // ---- phase 1: gather 16 nodes ----
    for (int g = 0; g < 16; ++g) {
        int v = nbase + g;
        int vc = min(v, n - 1);
        int start = rowptr[vc], cnt = degi[vc];
        float4 accA = {0.f, 0.f, 0.f, 0.f}, accB = accA;
        if (cnt > 0 && cnt <= 64) {
            int pre = ents[start + min(lane, cnt - 1)];
            int ng = cnt >> 3;
#pragma unroll 2
            for (int q = 0; q < ng; ++q) {
                unsigned s = ((unsigned)__shfl(pre, q * 8 + eg)) >> BSHIFT;
                float4 a, b; h8load(&h1s[(size_t)s * 64 + fq], a, b);
                f4add(accA, a); f4add(accB, b);
            }
            int rem = cnt & 7, j0 = cnt & ~7;
            if (rem) {
                unsigned s = ((unsigned)__shfl(pre, j0 + (eg < rem ? eg : 0))) >> BSHIFT;
                float4 a, b; h8load(&h1s[(size_t)s * 64 + fq], a, b);
                if (eg < rem) { f4add(accA, a); f4add(accB, b); }
            }
        } else if (cnt > 64) {
            int j = 0;
            for (; j + 8 <= cnt; j += 8) {
                unsigned s = ((unsigned)ents[start + j + eg]) >> BSHIFT;
                float4 a, b; h8load(&h1s[(size_t)s * 64 + fq], a, b);
                f4add(accA, a); f4add(accB, b);
            }
            int rem = cnt - j;
            if (rem) {
                unsigned s = ((unsigned)ents[start + j + (eg < rem ? eg : 0)]) >> BSHIFT;
                float4 a, b; h8load(&h1s[(size_t)s * 64 + fq], a, b);
                if (eg < rem) { f4add(accA, a); f4add(accB, b); }
            }
        }
        if (eg == 0) {                 // self loop
            float4 a, b; h8load(&h1s[(size_t)vc * 64 + fq], a, b);
            f4add(accA, a); f4add(accB, b);
        }
        f4red(accA, 8);  f4red(accB, 8);
        f4red(accA, 16); f4red(accB, 16);
        f4red(accA, 32); f4red(accB, 32);
        float d = dis[vc];
        if (eg == 0) {
            float4 bq0 = *(const float4*)&b1[fq];
            float4 bq1 = *(const float4*)&b1[fq + 4];
            float4 o0, o1;
            o0.x = fmaxf(fmaf(d, accA.x, bq0.x), 0.f);
            o0.y = fmaxf(fmaf(d, accA.y, bq0.y), 0.f);
            o0.z = fmaxf(fmaf(d, accA.z, bq0.z), 0.f);
            o0.w = fmaxf(fmaf(d, accA.w, bq0.w), 0.f);
            o1.x = fmaxf(fmaf(d, accB.x, bq1.x), 0.f);
            o1.y = fmaxf(fmaf(d, accB.y, bq1.y), 0.f);
            o1.z = fmaxf(fmaf(d, accB.z, bq1.z), 0.f);
            o1.w = fmaxf(fmaf(d, accB.w, bq1.w), 0.f);
            *(float4*)&h1row[wid][g][fq] = o0;
            *(float4*)&h1row[wid][g][fq + 4] = o1;
        }
        if (lane == 0) disW[wid][g] = d;
    }
    __syncthreads();
    // ---- phase 2: gemm2 for this wave's 16 rows ----
    for (int g = 0; g < 16; ++g) {
        const float* row = &h1row[wid][g][hh * 32];
        float p = 0.f;
#pragma unroll
        for (int j = 0; j < 32; j += 4) {
            float4 hv = *(const float4*)&row[j];
            p = fmaf(hv.x, w2r[j + 0], p);
            p = fmaf(hv.y, w2r[j + 1], p);
            p = fmaf(hv.z, w2r[j + 2], p);
            p = fmaf(hv.w, w2r[j + 3], p);
        }
        p += __shfl_xor(p, 32);
        int v = nbase + g;
        if (hh == 0 && v < n)
            h2s[(size_t)v * 32 + c] = __float2half(p * disW[wid][g]);
    }
}

// layer-2 aggregation + relu + FC head.  fp16 row = 64 B = 4 lanes x 16 B:
// eg = lane>>2 (16 edge slots), fq = (lane&3)*8 halves; one dwordx4 covers
// 16 edges per instruction.  xor-4/8/16/32 reduce; FC in lanes 0-3.
__global__ void k_agg2(const __half* __restrict__ h2s, const int* __restrict__ ents,
                       const int* __restrict__ rowptr, const int* __restrict__ degi,
                       const float* __restrict__ dis, const float* __restrict__ b2,
                       const float* __restrict__ Wfc, const float* __restrict__ bfc,
                       float* __restrict__ out, int n) {
    int wid = threadIdx.x >> 6, lane = threadIdx.x & 63;
    int v = blockIdx.x * 4 + wid;
    if (v >= n) return;
    int start = rowptr[v], cnt = degi[v];
    int eg = lane >> 2;
    int fq = (lane & 3) * 8;
    float4 accA = {0.f, 0.f, 0.f, 0.f}, accB = accA;
    if (cnt > 0 && cnt <= 64) {
        int pre = ents[start + min(lane, cnt - 1)];
        int ng = cnt >> 4;
#pragma unroll 2
        for (int g = 0; g < ng; ++g) {
            unsigned s = ((unsigned)__shfl(pre, g * 16 + eg)) >> BSHIFT;
            float4 a, b; h8load(&h2s[(size_t)s * 32 + fq], a, b);
            f4add(accA, a); f4add(accB, b);
        }
        int rem = cnt & 15, j0 = cnt & ~15;
        if (rem) {
            unsigned s = ((unsigned)__shfl(pre, j0 + (eg < rem ? eg : 0))) >> BSHIFT;
            float4 a, b; h8load(&h2s[(size_t)s * 32 + fq], a, b);
            if (eg < rem) { f4add(accA, a); f4add(accB, b); }
        }
    } else if (cnt > 64) {
        int j = 0;
        for (; j + 16 <= cnt; j += 16) {
            unsigned s = ((unsigned)ents[start + j + eg]) >> BSHIFT;
            float4 a, b; h8load(&h2s[(size_t)s * 32 + fq], a, b);
            f4add(accA, a); f4add(accB, b);
        }
        int rem = cnt - j;
        if (rem) {
            unsigned s = ((unsigned)ents[start + j + (eg < rem ? eg : 0)]) >> BSHIFT;
            float4 a, b; h8load(&h2s[(size_t)s * 32 + fq], a, b);
            if (eg < rem) { f4add(accA, a); f4add(accB, b); }
        }
    }
    if (eg == 0) {                     // self loop (lanes 0-3)
        float4 a, b; h8load(&h2s[(size_t)v * 32 + fq], a, b);
        f4add(accA, a); f4add(accB, b);
    }
    f4red(accA, 4);  f4red(accB, 4);
    f4red(accA, 8);  f4red(accB, 8);
    f4red(accA, 16); f4red(accB, 16);
    f4red(accA, 32); f4red(accB, 32);
    float p = 0.f;
    if (eg == 0) {
        float d = dis[v];
        float4 bq0 = *(const float4*)&b2[fq];
        float4 bq1 = *(const float4*)&b2[fq + 4];
        float4 wq0 = *(const float4*)&Wfc[fq];
        float4 wq1 = *(const float4*)&Wfc[fq + 4];
        p  = fmaxf(fmaf(d, accA.x, bq0.x), 0.f) * wq0.x;
        p += fmaxf(fmaf(d, accA.y, bq0.y), 0.f) * wq0.y;
        p += fmaxf(fmaf(d, accA.z, bq0.z), 0.f) * wq0.z;
        p += fmaxf(fmaf(d, accA.w, bq0.w), 0.f) * wq0.w;
        p += fmaxf(fmaf(d, accB.x, bq1.x), 0.f) * wq1.x;
        p += fmaxf(fmaf(d, accB.y, bq1.y), 0.f) * wq1.y;
        p += fmaxf(fmaf(d, accB.z, bq1.z), 0.f) * wq1.z;
        p += fmaxf(fmaf(d, accB.w, bq1.w), 0.f) * wq1.w;
    }
    p += __shfl_xor(p, 1); p += __shfl_xor(p, 2);
    if (lane == 0) out[v] = p + bfc[0];
}

extern "C" void kernel_launch(void* const* d_in, const int* in_sizes, int n_in,
                              void* d_out, int out_size, void* d_ws, size_t ws_size,
                              hipStream_t stream) {
    const float* x   = (const float*)d_in[0];
    const int*   ei  = (const int*)d_in[1];
    const float* W1  = (const float*)d_in[2];
    const float* b1  = (const float*)d_in[3];
    const float* W2  = (const float*)d_in[4];
    const float* b2  = (const float*)d_in[5];
    const float* Wfc = (const float*)d_in[6];
    const float* bfc = (const float*)d_in[7];
    float* out = (float*)d_out;

    const int n = in_sizes[0] / 128;       // 100000
    const int e = in_sizes[1] / 2;         // 3200000
    const int* src = ei;
    const int* dst = ei + e;

    const int nbuck = (n + BSIZE - 1) / BSIZE;           // 782
    const int m = nbuck * B1;                            // 200192
    const int echunk = (e + B1 - 1) / B1;                // 12500

    char* p = (char*)d_ws;
    size_t off = 0;
    auto carve = [&](size_t bytes) { void* r = p + off; off = (off + bytes + 255) & ~(size_t)255; return r; };
    int*   ghist   = (int*)  carve((size_t)m * 4);
    int*   ghist_s = (int*)  carve((size_t)m * 4);
    int*   part    = (int*)  carve(256 * 4);
    float* dis     = (float*)carve((size_t)n * 4);
    int*   rowptr  = (int*)  carve((size_t)n * 4);
    int*   degi    = (int*)  carve((size_t)n * 4);
    int*   ebuf2   = (int*)  carve((size_t)e * 4);
    __half* h2s    = (__half*)carve((size_t)n * 32 * 2);
    void*  ebuf_or_h1s = carve((size_t)e * 4);           // ebuf(E*4) aliases h1s(N*64*2)
    int*    ebuf = (int*)ebuf_or_h1s;
    __half* h1s  = (__half*)ebuf_or_h1s;
    (void)ws_size;

    const int nblk_scan = (m + SCAN_CHUNK - 1) / SCAN_CHUNK;   // 196 (<=256)
    const size_t lds_buck = (size_t)nbuck * 4;

    k_hist<<<B1, 256, lds_buck, stream>>>(dst, ghist, e, echunk, nbuck);
    k_gscan1<<<nblk_scan, 256, 0, stream>>>(ghist, part, m);
    k_gscan2<<<nblk_scan, 256, 0, stream>>>(ghist, part, ghist_s, m, nblk_scan);
    k_binscatter<<<B1, 256, lds_buck, stream>>>(src, dst, ghist_s, ebuf, e, echunk, nbuck);
    k_csr<<<nbuck, 256, 0, stream>>>(ebuf, ghist_s, ebuf2, rowptr, degi, dis, n, e, nbuck);
    k_gemm1<<<(n + 63) / 64, 256, 0, stream>>>(x, W1, dis, h1s, n);
    k_agg12<<<(n + 63) / 64, 256, 0, stream>>>(h1s, ebuf2, rowptr, degi, dis, b1, W2, h2s, n);
    k_agg2<<<(n + 3) / 4, 256, 0, stream>>>(h2s, ebuf2, rowptr, degi, dis, b2, Wfc, bfc, out, n);
}

// Round 14
// 305.462 us; speedup vs baseline: 1.1712x; 1.1712x over previous
//
#include <hip/hip_runtime.h>
#include <hip/hip_bf16.h>
#include <hip/hip_fp16.h>

// GCN: h = relu(GCN(x,W1,b1)); h = relu(GCN(h,W2,b2)); out = h @ Wfc + bfc
// GCN(x,W,b)[d] = dis[d] * ( sum_{(s,d) in E} hs[s] + hs[d] ) + b
//   where hs[v] = (x[v]@W) * dis[v],  dis[v] = rsqrt(1 + indeg(v))
//
// Round-14: revert k_agg12 to the round-12 one-node-per-wave form (25K
// blocks -- round-13's 64-node batching collapsed occupancy 79->38% and
// regressed 74->120 us).  New: k_csr stages each bucket's edges in LDS
// (int ds_add counting sort) and writes ebuf2 coalesced -- removes the
// second global read of ebuf and all scattered 4-B global writes.

#define SCAN_CHUNK 1024
#define BSHIFT 7
#define BSIZE 128            // dsts per bucket
#define B1 256               // blocks in hist/binscatter passes
#define CSR_CAP 5120         // max staged bucket size (avg ~4092, +5sigma ~4400)

__device__ inline void f4fma(float4& a, float s, const float4& b) {
    a.x = fmaf(s, b.x, a.x); a.y = fmaf(s, b.y, a.y);
    a.z = fmaf(s, b.z, a.z); a.w = fmaf(s, b.w, a.w);
}
__device__ inline void f4add(float4& a, const float4& b) {
    a.x += b.x; a.y += b.y; a.z += b.z; a.w += b.w;
}
__device__ inline void f4red(float4& a, int off) {
    a.x += __shfl_xor(a.x, off); a.y += __shfl_xor(a.y, off);
    a.z += __shfl_xor(a.z, off); a.w += __shfl_xor(a.w, off);
}
// 8 halves (16 B) -> two float4 (single dwordx4 load)
__device__ inline void h8load(const __half* p, float4& a, float4& b) {
    uint4 r = *(const uint4*)p;
    __half2* h = (__half2*)&r;
    float2 f0 = __half22float2(h[0]);
    float2 f1 = __half22float2(h[1]);
    float2 f2 = __half22float2(h[2]);
    float2 f3 = __half22float2(h[3]);
    a = make_float4(f0.x, f0.y, f1.x, f1.y);
    b = make_float4(f2.x, f2.y, f3.x, f3.y);
}
__device__ inline void h4store(__half* p, float4 v) {
    __half2 a = __floats2half2_rn(v.x, v.y);
    __half2 b = __floats2half2_rn(v.z, v.w);
    uint2 r; r.x = *(uint*)&a; r.y = *(uint*)&b;
    *(uint2*)p = r;
}

// ---- generic exclusive scan (m ints, nblk = ceil(m/1024) <= 256) ----
__global__ void k_gscan1(const int* __restrict__ in, int* __restrict__ part, int m) {
    int t = threadIdx.x;
    int base = blockIdx.x * SCAN_CHUNK + t * 4;
    int s = 0;
    for (int u = 0; u < 4; ++u) { int i = base + u; if (i < m) s += in[i]; }
    for (int o = 32; o; o >>= 1) s += __shfl_down(s, o);
    __shared__ int ws[4];
    if ((t & 63) == 0) ws[t >> 6] = s;
    __syncthreads();
    if (t == 0) part[blockIdx.x] = ws[0] + ws[1] + ws[2] + ws[3];
}

__global__ void k_gscan2(const int* __restrict__ in, const int* __restrict__ part,
                         int* __restrict__ out, int m, int nblk) {
    int t = threadIdx.x;
    int b = blockIdx.x;
    int pv = (t < b && t < nblk) ? part[t] : 0;
    int ps = pv;
    for (int o = 32; o; o >>= 1) ps += __shfl_down(ps, o);
    __shared__ int sh[4];
    if ((t & 63) == 0) sh[t >> 6] = ps;
    __syncthreads();
    int blockoff = sh[0] + sh[1] + sh[2] + sh[3];

    int base = b * SCAN_CHUNK + t * 4;
    int v0 = 0, v1 = 0, v2 = 0, v3 = 0;
    if (base + 0 < m) v0 = in[base + 0];
    if (base + 1 < m) v1 = in[base + 1];
    if (base + 2 < m) v2 = in[base + 2];
    if (base + 3 < m) v3 = in[base + 3];
    int tot = v0 + v1 + v2 + v3;
    int lane = t & 63, wid = t >> 6;
    int incl = tot;
    for (int o = 1; o < 64; o <<= 1) { int u = __shfl_up(incl, o); if (lane >= o) incl += u; }
    int excl = incl - tot;
    __shared__ int wt[4];
    if (lane == 63) wt[wid] = incl;
    __syncthreads();
    int woff = 0;
    for (int w = 0; w < wid; ++w) woff += wt[w];
    int off = blockoff + woff + excl;
    if (base + 0 < m) out[base + 0] = off;
    if (base + 1 < m) out[base + 1] = off + v0;
    if (base + 2 < m) out[base + 2] = off + v0 + v1;
    if (base + 3 < m) out[base + 3] = off + v0 + v1 + v2;
}

// ---- pass 1a: per-block bucket histogram (LDS atomics, int4 reads) ----
__global__ __launch_bounds__(256) void k_hist(const int* __restrict__ dst,
                                              int* __restrict__ ghist,
                                              int e, int echunk, int nbuck) {
    extern __shared__ int h[];   // nbuck ints
    int t = threadIdx.x, b = blockIdx.x;
    for (int i = t; i < nbuck; i += 256) h[i] = 0;
    __syncthreads();
    int s = b * echunk, epd = min(e, s + echunk);
    for (int i = s + t * 4; i < epd; i += 1024) {
        if (i + 3 < epd) {
            int4 d4 = *(const int4*)&dst[i];
            atomicAdd(&h[d4.x >> BSHIFT], 1);
            atomicAdd(&h[d4.y >> BSHIFT], 1);
            atomicAdd(&h[d4.z >> BSHIFT], 1);
            atomicAdd(&h[d4.w >> BSHIFT], 1);
        } else {
            for (int u = i; u < epd; ++u) atomicAdd(&h[dst[u] >> BSHIFT], 1);
        }
    }
    __syncthreads();
    for (int k = t; k < nbuck; k += 256)
        ghist[k * B1 + b] = h[k];
}

// ---- pass 1b: scatter packed (src<<7|dlow) into bucket-ordered ebuf ----
__global__ __launch_bounds__(256) void k_binscatter(
        const int* __restrict__ src, const int* __restrict__ dst,
        const int* __restrict__ ghist_s, int* __restrict__ ebuf,
        int e, int echunk, int nbuck) {
    extern __shared__ int cur[];   // nbuck ints
    int t = threadIdx.x, b = blockIdx.x;
    for (int k = t; k < nbuck; k += 256)
        cur[k] = ghist_s[k * B1 + b];
    __syncthreads();
    int s = b * echunk, epd = min(e, s + echunk);
    for (int i = s + t * 4; i < epd; i += 1024) {
        if (i + 3 < epd) {
            int4 d4 = *(const int4*)&dst[i];
            int4 s4 = *(const int4*)&src[i];
            int p0 = atomicAdd(&cur[d4.x >> BSHIFT], 1);
            int p1 = atomicAdd(&cur[d4.y >> BSHIFT], 1);
            int p2 = atomicAdd(&cur[d4.z >> BSHIFT], 1);
            int p3 = atomicAdd(&cur[d4.w >> BSHIFT], 1);
            ebuf[p0] = (s4.x << BSHIFT) | (d4.x & (BSIZE - 1));
            ebuf[p1] = (s4.y << BSHIFT) | (d4.y & (BSIZE - 1));
            ebuf[p2] = (s4.z << BSHIFT) | (d4.z & (BSIZE - 1));
            ebuf[p3] = (s4.w << BSHIFT) | (d4.w & (BSIZE - 1));
        } else {
            for (int u = i; u < epd; ++u) {
                int d = dst[u];
                int pos = atomicAdd(&cur[d >> BSHIFT], 1);
                ebuf[pos] = (src[u] << BSHIFT) | (d & (BSIZE - 1));
            }
        }
    }
}

// ---- pass 2: per-bucket dst counting sort -> ebuf2 (bucket-local CSR) ----
// LDS-staged: one global read of the bucket segment, count/scan/scatter in
// LDS (native int ds_add), coalesced global write-out.  Fallback to the
// two-pass global path only for buckets > CSR_CAP (not expected).
__global__ __launch_bounds__(256) void k_csr(
        const int* __restrict__ ebuf, const int* __restrict__ ghist_s,
        int* __restrict__ ebuf2, int* __restrict__ rowptr, int* __restrict__ degi,
        float* __restrict__ dis, int n, int e, int nbuck) {
    int k = blockIdx.x, t = threadIdx.x;
    int estart = ghist_s[k * B1];
    int eend = (k + 1 < nbuck) ? ghist_s[(k + 1) * B1] : e;
    int ecnt = eend - estart;
    __shared__ int ein[CSR_CAP];
    __shared__ int eout[CSR_CAP];
    __shared__ int cnt[BSIZE];
    __shared__ int cur[BSIZE];
    __shared__ int wt[4];
    if (t < BSIZE) cnt[t] = 0;
    bool staged = (ecnt <= CSR_CAP);
    if (staged) {
        for (int i = t; i < ecnt; i += 256) ein[i] = ebuf[estart + i];
    }
    __syncthreads();
    if (staged) {
        for (int i = t; i < ecnt; i += 256)
            atomicAdd(&cnt[ein[i] & (BSIZE - 1)], 1);
    } else {
        for (int i = estart + t; i < eend; i += 256)
            atomicAdd(&cnt[ebuf[i] & (BSIZE - 1)], 1);
    }
    __syncthreads();
    int v = (t < BSIZE) ? cnt[t] : 0;
    int lane = t & 63, wid = t >> 6;
    int incl = v;
    for (int o = 1; o < 64; o <<= 1) { int u = __shfl_up(incl, o); if (lane >= o) incl += u; }
    if (lane == 63) wt[wid] = incl;
    __syncthreads();
    int woff = (wid == 1) ? wt[0] : 0;
    int excl = woff + incl - v;
    if (t < BSIZE) {
        cur[t] = excl;                       // bucket-local offset
        int node = k * BSIZE + t;
        if (node < n) {
            rowptr[node] = estart + excl;
            degi[node]   = v;
            dis[node]    = rsqrtf((float)(v + 1));
        }
    }
    __syncthreads();
    if (staged) {
        for (int i = t; i < ecnt; i += 256) {
            int w = ein[i];
            int pos = atomicAdd(&cur[w & (BSIZE - 1)], 1);
            eout[pos] = w;                   // scatter stays in LDS
        }
        __syncthreads();
        for (int i = t; i < ecnt; i += 256)  // coalesced write-out
            ebuf2[estart + i] = eout[i];
    } else {
        for (int i = estart + t; i < eend; i += 256) {
            int w = ebuf[i];
            int pos = estart + atomicAdd(&cur[w & (BSIZE - 1)], 1);
            ebuf2[pos] = w;
        }
    }
}

// h1s = fp16( (x @ W1) * dis ) — outer-product GEMM, block tile 64x64, K=128.
#define SA 132
__global__ __launch_bounds__(256) void k_gemm1(
        const float* __restrict__ x, const float* __restrict__ W1,
        const float* __restrict__ dis, __half* __restrict__ h1s, int n) {
    __shared__ float Xs[64 * SA];    // 33 KB
    __shared__ float Ws[128 * 64];   // 32 KB
    int t = threadIdx.x;
    int nbase = blockIdx.x * 64;
    for (int i = t; i < 2048; i += 256)
        ((float4*)Ws)[i] = ((const float4*)W1)[i];
    for (int i = t; i < 2048; i += 256) {
        int row = i >> 5, q = i & 31;
        int r = nbase + row; if (r >= n) r = n - 1;
        float4 v = ((const float4*)(x + (size_t)r * 128))[q];
        *(float4*)&Xs[row * SA + q * 4] = v;
    }
    __syncthreads();
    int wid = t >> 6, lane = t & 63;
    int lx = lane & 7, ly = lane >> 3;
    int wm = wid & 1, wn = wid >> 1;
    int row0 = wm * 32 + ly * 4;
    int col0 = wn * 32 + lx * 4;
    float4 acc0 = {0.f,0.f,0.f,0.f}, acc1 = acc0, acc2 = acc0, acc3 = acc0;
#pragma unroll 4
    for (int k4 = 0; k4 < 32; ++k4) {
        int k = k4 * 4;
        float4 a0 = *(const float4*)&Xs[(row0 + 0) * SA + k];
        float4 a1 = *(const float4*)&Xs[(row0 + 1) * SA + k];
        float4 a2 = *(const float4*)&Xs[(row0 + 2) * SA + k];
        float4 a3 = *(const float4*)&Xs[(row0 + 3) * SA + k];
        float4 b0 = *(const float4*)&Ws[(k + 0) * 64 + col0];
        float4 b1 = *(const float4*)&Ws[(k + 1) * 64 + col0];
        float4 b2 = *(const float4*)&Ws[(k + 2) * 64 + col0];
        float4 b3 = *(const float4*)&Ws[(k + 3) * 64 + col0];
        f4fma(acc0, a0.x, b0); f4fma(acc0, a0.y, b1); f4fma(acc0, a0.z, b2); f4fma(acc0, a0.w, b3);
        f4fma(acc1, a1.x, b0); f4fma(acc1, a1.y, b1); f4fma(acc1, a1.z, b2); f4fma(acc1, a1.w, b3);
        f4fma(acc2, a2.x, b0); f4fma(acc2, a2.y, b1); f4fma(acc2, a2.z, b2); f4fma(acc2, a2.w, b3);
        f4fma(acc3, a3.x, b0); f4fma(acc3, a3.y, b1); f4fma(acc3, a3.z, b2); f4fma(acc3, a3.w, b3);
    }
    int grow = nbase + row0;
#pragma unroll
    for (int r = 0; r < 4; ++r) {
        int rr = grow + r;
        if (rr < n) {
            float d = dis[rr];
            float4 o = (r == 0) ? acc0 : (r == 1) ? acc1 : (r == 2) ? acc2 : acc3;
            o.x *= d; o.y *= d; o.z *= d; o.w *= d;
            h4store(&h1s[(size_t)rr * 64 + col0], o);
        }
    }
}

// Layer-1 aggregation + relu/b1 + gemm2, all in-wave (round-12 form: one
// node per wave, 25K blocks for occupancy).  fp16 row = 128 B = 8 lanes x
// 16 B: eg = lane>>3 (8 edge slots), fq = (lane&7)*8; one dwordx4 covers 8
// edges.  xor-8/16/32 reduce -> lanes 0-7 hold h1r -> relu -> LDS row ->
// in-wave gemm2 (W2 column in registers) -> h2s (fp16).
__global__ __launch_bounds__(256) void k_agg12(
        const __half* __restrict__ h1s, const int* __restrict__ ents,
        const int* __restrict__ rowptr, const int* __restrict__ degi,
        const float* __restrict__ dis, const float* __restrict__ b1,
        const float* __restrict__ W2, __half* __restrict__ h2s, int n) {
    __shared__ float h1row[4][72];
    int wid = threadIdx.x >> 6, lane = threadIdx.x & 63;
    int v = blockIdx.x * 4 + wid;
    int vc = min(v, n - 1);            // no early return (syncthreads below)
    int start = rowptr[vc], cnt = degi[vc];
    int eg = lane >> 3;
    int fq = (lane & 7) * 8;           // half-index of this lane's 8 features
    int c = lane & 31, hh = lane >> 5;
    // preload W2 column c, k-range [hh*32, hh*32+32) -> 32 VGPRs
    float w2r[32];
#pragma unroll
    for (int j = 0; j < 32; ++j)
        w2r[j] = W2[(hh * 32 + j) * 32 + c];
    float4 accA = {0.f, 0.f, 0.f, 0.f}, accB = accA;
    if (cnt > 0 && cnt <= 64) {
        int pre = ents[start + min(lane, cnt - 1)];
        int ng = cnt >> 3;
#pragma unroll 2
        for (int g = 0; g < ng; ++g) {
            unsigned s = ((unsigned)__shfl(pre, g * 8 + eg)) >> BSHIFT;
            float4 a, b; h8load(&h1s[(size_t)s * 64 + fq], a, b);
            f4add(accA, a); f4add(accB, b);
        }
        int rem = cnt & 7, j0 = cnt & ~7;
        if (rem) {
            unsigned s = ((unsigned)__shfl(pre, j0 + (eg < rem ? eg : 0))) >> BSHIFT;
            float4 a, b; h8load(&h1s[(size_t)s * 64 + fq], a, b);
            if (eg < rem) { f4add(accA, a); f4add(accB, b); }
        }
    } else if (cnt > 64) {
        int j = 0;
        for (; j + 8 <= cnt; j += 8) {
            unsigned s = ((unsigned)ents[start + j + eg]) >> BSHIFT;
            float4 a, b; h8load(&h1s[(size_t)s * 64 + fq], a, b);
            f4add(accA, a); f4add(accB, b);
        }
        int rem = cnt - j;
        if (rem) {
            unsigned s = ((unsigned)ents[start + j + (eg < rem ? eg : 0)]) >> BSHIFT;
            float4 a, b; h8load(&h1s[(size_t)s * 64 + fq], a, b);
            if (eg < rem) { f4add(accA, a); f4add(accB, b); }
        }
    }
    if (eg == 0) {                     // self loop
        float4 a, b; h8load(&h1s[(size_t)vc * 64 + fq], a, b);
        f4add(accA, a); f4add(accB, b);
    }
    f4red(accA, 8);  f4red(accB, 8);
    f4red(accA, 16); f4red(accB, 16);
    f4red(accA, 32); f4red(accB, 32);
    float d = dis[vc];
    if (eg == 0) {
        float4 bq0 = *(const float4*)&b1[fq];
        float4 bq1 = *(const float4*)&b1[fq + 4];
        float4 o0, o1;
        o0.x = fmaxf(fmaf(d, accA.x, bq0.x), 0.f);
        o0.y = fmaxf(fmaf(d, accA.y, bq0.y), 0.f);
        o0.z = fmaxf(fmaf(d, accA.z, bq0.z), 0.f);
        o0.w = fmaxf(fmaf(d, accA.w, bq0.w), 0.f);
        o1.x = fmaxf(fmaf(d, accB.x, bq1.x), 0.f);
        o1.y = fmaxf(fmaf(d, accB.y, bq1.y), 0.f);
        o1.z = fmaxf(fmaf(d, accB.z, bq1.z), 0.f);
        o1.w = fmaxf(fmaf(d, accB.w, bq1.w), 0.f);
        *(float4*)&h1row[wid][fq] = o0;
        *(float4*)&h1row[wid][fq + 4] = o1;
    }
    __syncthreads();     // orders each wave's LDS row write before its reads
    // gemm2 in-wave: lane computes h2[c] partial over its k-half
    float p = 0.f;
#pragma unroll
    for (int j = 0; j < 32; j += 4) {
        float4 hv = *(const float4*)&h1row[wid][hh * 32 + j];
        p = fmaf(hv.x, w2r[j + 0], p);
        p = fmaf(hv.y, w2r[j + 1], p);
        p = fmaf(hv.z, w2r[j + 2], p);
        p = fmaf(hv.w, w2r[j + 3], p);
    }
    p += __shfl_xor(p, 32);
    if (hh == 0 && v < n) h2s[(size_t)v * 32 + c] = __float2half(p * d);
}

// layer-2 aggregation + relu + FC head.  fp16 row = 64 B = 4 lanes x 16 B:
// eg = lane>>2 (16 edge slots), fq = (lane&3)*8 halves; one dwordx4 covers
// 16 edges per instruction.  xor-4/8/16/32 reduce; FC in lanes 0-3.
__global__ void k_agg2(const __half* __restrict__ h2s, const int* __restrict__ ents,
                       const int* __restrict__ rowptr, const int* __restrict__ degi,
                       const float* __restrict__ dis, const float* __restrict__ b2,
                       const float* __restrict__ Wfc, const float* __restrict__ bfc,
                       float* __restrict__ out, int n) {
    int wid = threadIdx.x >> 6, lane = threadIdx.x & 63;
    int v = blockIdx.x * 4 + wid;
    if (v >= n) return;
    int start = rowptr[v], cnt = degi[v];
    int eg = lane >> 2;
    int fq = (lane & 3) * 8;
    float4 accA = {0.f, 0.f, 0.f, 0.f}, accB = accA;
    if (cnt > 0 && cnt <= 64) {
        int pre = ents[start + min(lane, cnt - 1)];
        int ng = cnt >> 4;
#pragma unroll 2
        for (int g = 0; g < ng; ++g) {
            unsigned s = ((unsigned)__shfl(pre, g * 16 + eg)) >> BSHIFT;
            float4 a, b; h8load(&h2s[(size_t)s * 32 + fq], a, b);
            f4add(accA, a); f4add(accB, b);
        }
        int rem = cnt & 15, j0 = cnt & ~15;
        if (rem) {
            unsigned s = ((unsigned)__shfl(pre, j0 + (eg < rem ? eg : 0))) >> BSHIFT;
            float4 a, b; h8load(&h2s[(size_t)s * 32 + fq], a, b);
            if (eg < rem) { f4add(accA, a); f4add(accB, b); }
        }
    } else if (cnt > 64) {
        int j = 0;
        for (; j + 16 <= cnt; j += 16) {
            unsigned s = ((unsigned)ents[start + j + eg]) >> BSHIFT;
            float4 a, b; h8load(&h2s[(size_t)s * 32 + fq], a, b);
            f4add(accA, a); f4add(accB, b);
        }
        int rem = cnt - j;
        if (rem) {
            unsigned s = ((unsigned)ents[start + j + (eg < rem ? eg : 0)]) >> BSHIFT;
            float4 a, b; h8load(&h2s[(size_t)s * 32 + fq], a, b);
            if (eg < rem) { f4add(accA, a); f4add(accB, b); }
        }
    }
    if (eg == 0) {                     // self loop (lanes 0-3)
        float4 a, b; h8load(&h2s[(size_t)v * 32 + fq], a, b);
        f4add(accA, a); f4add(accB, b);
    }
    f4red(accA, 4);  f4red(accB, 4);
    f4red(accA, 8);  f4red(accB, 8);
    f4red(accA, 16); f4red(accB, 16);
    f4red(accA, 32); f4red(accB, 32);
    float p = 0.f;
    if (eg == 0) {
        float d = dis[v];
        float4 bq0 = *(const float4*)&b2[fq];
        float4 bq1 = *(const float4*)&b2[fq + 4];
        float4 wq0 = *(const float4*)&Wfc[fq];
        float4 wq1 = *(const float4*)&Wfc[fq + 4];
        p  = fmaxf(fmaf(d, accA.x, bq0.x), 0.f) * wq0.x;
        p += fmaxf(fmaf(d, accA.y, bq0.y), 0.f) * wq0.y;
        p += fmaxf(fmaf(d, accA.z, bq0.z), 0.f) * wq0.z;
        p += fmaxf(fmaf(d, accA.w, bq0.w), 0.f) * wq0.w;
        p += fmaxf(fmaf(d, accB.x, bq1.x), 0.f) * wq1.x;
        p += fmaxf(fmaf(d, accB.y, bq1.y), 0.f) * wq1.y;
        p += fmaxf(fmaf(d, accB.z, bq1.z), 0.f) * wq1.z;
        p += fmaxf(fmaf(d, accB.w, bq1.w), 0.f) * wq1.w;
    }
    p += __shfl_xor(p, 1); p += __shfl_xor(p, 2);
    if (lane == 0) out[v] = p + bfc[0];
}

extern "C" void kernel_launch(void* const* d_in, const int* in_sizes, int n_in,
                              void* d_out, int out_size, void* d_ws, size_t ws_size,
                              hipStream_t stream) {
    const float* x   = (const float*)d_in[0];
    const int*   ei  = (const int*)d_in[1];
    const float* W1  = (const float*)d_in[2];
    const float* b1  = (const float*)d_in[3];
    const float* W2  = (const float*)d_in[4];
    const float* b2  = (const float*)d_in[5];
    const float* Wfc = (const float*)d_in[6];
    const float* bfc = (const float*)d_in[7];
    float* out = (float*)d_out;

    const int n = in_sizes[0] / 128;       // 100000
    const int e = in_sizes[1] / 2;         // 3200000
    const int* src = ei;
    const int* dst = ei + e;

    const int nbuck = (n + BSIZE - 1) / BSIZE;           // 782
    const int m = nbuck * B1;                            // 200192
    const int echunk = (e + B1 - 1) / B1;                // 12500

    char* p = (char*)d_ws;
    size_t off = 0;
    auto carve = [&](size_t bytes) { void* r = p + off; off = (off + bytes + 255) & ~(size_t)255; return r; };
    int*   ghist   = (int*)  carve((size_t)m * 4);
    int*   ghist_s = (int*)  carve((size_t)m * 4);
    int*   part    = (int*)  carve(256 * 4);
    float* dis     = (float*)carve((size_t)n * 4);
    int*   rowptr  = (int*)  carve((size_t)n * 4);
    int*   degi    = (int*)  carve((size_t)n * 4);
    int*   ebuf2   = (int*)  carve((size_t)e * 4);
    __half* h2s    = (__half*)carve((size_t)n * 32 * 2);
    void*  ebuf_or_h1s = carve((size_t)e * 4);           // ebuf(E*4) aliases h1s(N*64*2)
    int*    ebuf = (int*)ebuf_or_h1s;
    __half* h1s  = (__half*)ebuf_or_h1s;
    (void)ws_size;

    const int nblk_scan = (m + SCAN_CHUNK - 1) / SCAN_CHUNK;   // 196 (<=256)
    const size_t lds_buck = (size_t)nbuck * 4;

    k_hist<<<B1, 256, lds_buck, stream>>>(dst, ghist, e, echunk, nbuck);
    k_gscan1<<<nblk_scan, 256, 0, stream>>>(ghist, part, m);
    k_gscan2<<<nblk_scan, 256, 0, stream>>>(ghist, part, ghist_s, m, nblk_scan);
    k_binscatter<<<B1, 256, lds_buck, stream>>>(src, dst, ghist_s, ebuf, e, echunk, nbuck);
    k_csr<<<nbuck, 256, 0, stream>>>(ebuf, ghist_s, ebuf2, rowptr, degi, dis, n, e, nbuck);
    k_gemm1<<<(n + 63) / 64, 256, 0, stream>>>(x, W1, dis, h1s, n);
    k_agg12<<<(n + 3) / 4, 256, 0, stream>>>(h1s, ebuf2, rowptr, degi, dis, b1, W2, h2s, n);
    k_agg2<<<(n + 3) / 4, 256, 0, stream>>>(h2s, ebuf2, rowptr, degi, dis, b2, Wfc, bfc, out, n);
}